// Round 12
// baseline (597.688 us; speedup 1.0000x reference)
//
#include <hip/hip_runtime.h>

#define N_NODES 100000
#define F 64
#define SCAN_TPB 256
#define SCAN_ELEMS 1024

// ---------------- CSR build ----------------
__global__ void hist_kernel(const int* __restrict__ dst, int* __restrict__ cnt, int E) {
    int i = blockIdx.x * blockDim.x + threadIdx.x;
    if (i < E) atomicAdd(&cnt[dst[i]], 1);
}

__global__ void scan1_kernel(const int* __restrict__ cnt, int* __restrict__ excl,
                             int* __restrict__ bsum, int n) {
    __shared__ int sh[SCAN_TPB];
    const int t = threadIdx.x;
    const int base = blockIdx.x * SCAN_ELEMS + t * 4;
    int v0 = (base + 0 < n) ? cnt[base + 0] : 0;
    int v1 = (base + 1 < n) ? cnt[base + 1] : 0;
    int v2 = (base + 2 < n) ? cnt[base + 2] : 0;
    int v3 = (base + 3 < n) ? cnt[base + 3] : 0;
    const int tot = v0 + v1 + v2 + v3;
    sh[t] = tot; __syncthreads();
    for (int off = 1; off < SCAN_TPB; off <<= 1) {
        int x = (t >= off) ? sh[t - off] : 0;
        __syncthreads();
        sh[t] += x;
        __syncthreads();
    }
    int exc = sh[t] - tot;
    if (t == SCAN_TPB - 1) bsum[blockIdx.x] = sh[t];
    if (base + 0 < n) excl[base + 0] = exc;  exc += v0;
    if (base + 1 < n) excl[base + 1] = exc;  exc += v1;
    if (base + 2 < n) excl[base + 2] = exc;  exc += v2;
    if (base + 3 < n) excl[base + 3] = exc;
}

__global__ void scan2_kernel(int* __restrict__ bsum, int nb) {
    __shared__ int sh[SCAN_TPB];
    const int t = threadIdx.x;
    const int v = (t < nb) ? bsum[t] : 0;
    sh[t] = v; __syncthreads();
    for (int off = 1; off < SCAN_TPB; off <<= 1) {
        int x = (t >= off) ? sh[t - off] : 0;
        __syncthreads();
        sh[t] += x;
        __syncthreads();
    }
    if (t < nb) bsum[t] = sh[t] - v;   // exclusive
}

// finalize rowptr AND initialize cursor (removes the d2d memcpy)
__global__ void scan3_kernel(int* __restrict__ excl, const int* __restrict__ bsum,
                             int* __restrict__ cursor, int n, int E) {
    int i = blockIdx.x * blockDim.x + threadIdx.x;
    if (i < n) {
        int v = excl[i] + bsum[i / SCAN_ELEMS];
        excl[i]  = v;
        cursor[i] = v;
    }
    if (i == 0) excl[n] = E;   // rowptr[N] = E
}

// pack (src, w) pairs in ORIGINAL edge order: pure streaming, no scatter
__global__ void pack_kernel(const int* __restrict__ src, const float* __restrict__ ew,
                            int2* __restrict__ pair, int E) {
    int i = blockIdx.x * blockDim.x + threadIdx.x;
    if (i < E) pair[i] = make_int2(src[i], __float_as_int(ew[i]));
}

// minimal random scatter: 4B edge-id only (6.4MB footprint)
__global__ void reorder_perm(const int* __restrict__ dst, int* __restrict__ cursor,
                             int* __restrict__ perm, int E) {
    int i = blockIdx.x * blockDim.x + threadIdx.x;
    if (i >= E) return;
    int pos = atomicAdd(&cursor[dst[i]], 1);
    perm[pos] = i;
}

// ---------------- aggregation: gather per node (no atomics) ----------------
// PACKED: read (src,w) via one 8B load from pair[]; else two 4B loads from src/ew.
template <bool PACKED>
__global__ void gather_kernel(const float* __restrict__ xin, const int* __restrict__ rowptr,
                              const int* __restrict__ perm, const int2* __restrict__ pair,
                              const int* __restrict__ srcA, const float* __restrict__ ewA,
                              float* __restrict__ agg) {
    const int wid  = (blockIdx.x * blockDim.x + threadIdx.x) >> 6;  // node id
    const int lane = threadIdx.x & 63;
    if (wid >= N_NODES) return;
    const int beg = __builtin_amdgcn_readfirstlane(rowptr[wid]);
    const int end = __builtin_amdgcn_readfirstlane(rowptr[wid + 1]);
    float a[8] = {0.f, 0.f, 0.f, 0.f, 0.f, 0.f, 0.f, 0.f};
    int e = beg;
    for (; e + 8 <= end; e += 8) {            // 8 outstanding row fetches
        int   s[8];
        float w[8];
#pragma unroll
        for (int j = 0; j < 8; ++j) {
            const int i = perm[e + j];        // sequential broadcast loads
            if (PACKED) {
                const int2 p = pair[i];       // one random 8B
                s[j] = p.x; w[j] = __int_as_float(p.y);
            } else {
                s[j] = srcA[i]; w[j] = ewA[i];
            }
        }
#pragma unroll
        for (int j = 0; j < 8; ++j)
            a[j] += w[j] * xin[(size_t)s[j] * F + lane];   // coalesced 256B rows
    }
    for (; e < end; ++e) {
        const int i = perm[e];
        if (PACKED) {
            const int2 p = pair[i];
            a[0] += __int_as_float(p.y) * xin[(size_t)p.x * F + lane];
        } else {
            a[0] += ewA[i] * xin[(size_t)srcA[i] * F + lane];
        }
    }
    agg[(size_t)wid * F + lane] =
        ((a[0] + a[1]) + (a[2] + a[3])) + ((a[4] + a[5]) + (a[6] + a[7]));
}

// ---------------- dense: out = A@Wrel + b + X@Wroot, tiled ----------------
template <bool RELU>
__global__ void dense_tiled(const float* __restrict__ A,
                            const float* __restrict__ X,
                            const float* __restrict__ Wrel,
                            const float* __restrict__ Wroot,
                            const float* __restrict__ bias,
                            float* __restrict__ out) {
    __shared__ float sWr[F * F];
    __shared__ float sWo[F * F];
    __shared__ float sA[F * F];
    __shared__ float sX[F * F];

    const int t = threadIdx.x;
    for (int i = t; i < 1024; i += 256) {   // weights, row-major [k][c]
        reinterpret_cast<float4*>(sWr)[i] = reinterpret_cast<const float4*>(Wrel)[i];
        reinterpret_cast<float4*>(sWo)[i] = reinterpret_cast<const float4*>(Wroot)[i];
    }

    const int row0 = blockIdx.x * 64;
    for (int i = t; i < 1024; i += 256) {   // A,X tiles, XOR-swizzled
        const int r  = i >> 4;
        const int c4 = (i & 15) << 2;
        int rr = row0 + r; if (rr > N_NODES - 1) rr = N_NODES - 1;   // tail clamp
        const float4 av = *reinterpret_cast<const float4*>(A + (size_t)rr * F + c4);
        const float4 xv = *reinterpret_cast<const float4*>(X + (size_t)rr * F + c4);
        const int rbase = r * F, rx = r & 31;
        sA[rbase + ((c4 + 0) ^ rx)] = av.x;
        sA[rbase + ((c4 + 1) ^ rx)] = av.y;
        sA[rbase + ((c4 + 2) ^ rx)] = av.z;
        sA[rbase + ((c4 + 3) ^ rx)] = av.w;
        sX[rbase + ((c4 + 0) ^ rx)] = xv.x;
        sX[rbase + ((c4 + 1) ^ rx)] = xv.y;
        sX[rbase + ((c4 + 2) ^ rx)] = xv.z;
        sX[rbase + ((c4 + 3) ^ rx)] = xv.w;
    }
    __syncthreads();

    const int cg = (t & 15) << 2;
    const int rg = (t >> 4) << 2;
    float acc[4][4];
    {
        const float b0 = bias[cg], b1 = bias[cg + 1], b2 = bias[cg + 2], b3 = bias[cg + 3];
#pragma unroll
        for (int i = 0; i < 4; ++i) { acc[i][0] = b0; acc[i][1] = b1; acc[i][2] = b2; acc[i][3] = b3; }
    }
    int rbase[4], rxs[4];
#pragma unroll
    for (int i = 0; i < 4; ++i) { rbase[i] = (rg + i) * F; rxs[i] = (rg + i) & 31; }

#pragma unroll 4
    for (int k = 0; k < F; ++k) {
        const float4 wr = *reinterpret_cast<const float4*>(&sWr[k * F + cg]);
        const float4 wo = *reinterpret_cast<const float4*>(&sWo[k * F + cg]);
#pragma unroll
        for (int i = 0; i < 4; ++i) {
            const float a  = sA[rbase[i] + (k ^ rxs[i])];
            const float xv = sX[rbase[i] + (k ^ rxs[i])];
            acc[i][0] += a * wr.x + xv * wo.x;
            acc[i][1] += a * wr.y + xv * wo.y;
            acc[i][2] += a * wr.z + xv * wo.z;
            acc[i][3] += a * wr.w + xv * wo.w;
        }
    }

#pragma unroll
    for (int i = 0; i < 4; ++i) {
        const int n = row0 + rg + i;
        if (n < N_NODES) {
            float4 o;
            o.x = acc[i][0]; o.y = acc[i][1]; o.z = acc[i][2]; o.w = acc[i][3];
            if (RELU) {
                o.x = fmaxf(o.x, 0.f); o.y = fmaxf(o.y, 0.f);
                o.z = fmaxf(o.z, 0.f); o.w = fmaxf(o.w, 0.f);
            }
            *reinterpret_cast<float4*>(out + (size_t)n * F + cg) = o;
        }
    }
}

// ---------------- legacy atomic scatter (last-resort fallback) ----------------
__global__ void scatter_kernel(const float* __restrict__ xin,
                               const int* __restrict__ src,
                               const int* __restrict__ dst,
                               const float* __restrict__ ew,
                               float* __restrict__ agg, int E) {
    int gid  = blockIdx.x * blockDim.x + threadIdx.x;
    int eid  = gid >> 6;
    int lane = threadIdx.x & 63;
    if (eid >= E) return;
    float v = ew[eid] * xin[(size_t)src[eid] * F + lane];
    atomicAdd(&agg[(size_t)dst[eid] * F + lane], v);
}

extern "C" void kernel_launch(void* const* d_in, const int* in_sizes, int n_in,
                              void* d_out, int out_size, void* d_ws, size_t ws_size,
                              hipStream_t stream) {
    const float* x   = (const float*)d_in[0];
    const int*   ei  = (const int*)d_in[1];
    const float* ew  = (const float*)d_in[2];
    const float* W1r = (const float*)d_in[3];
    const float* b1  = (const float*)d_in[4];
    const float* W1o = (const float*)d_in[5];
    const float* W2r = (const float*)d_in[6];
    const float* b2  = (const float*)d_in[7];
    const float* W2o = (const float*)d_in[8];
    float*       out = (float*)d_out;

    const int E = in_sizes[2];
    const int* src = ei;
    const int* dst = ei + E;

    const int nScanBlocks = (N_NODES + SCAN_ELEMS - 1) / SCAN_ELEMS;   // 98
    const size_t aggB  = (size_t)N_NODES * F * sizeof(float);          // 25.6 MB
    const size_t permB = (size_t)E * 4;                                // 6.4 MB
    const size_t pairB = (size_t)E * 8;                                // 12.8 MB
    const size_t rpB   = (((size_t)(N_NODES + 1) * 4) + 15) & ~(size_t)15;
    const size_t curB  = (((size_t)N_NODES * 4) + 15) & ~(size_t)15;
    const size_t bsB   = (((size_t)nScanBlocks * 4) + 15) & ~(size_t)15;

    char* p = (char*)d_ws;
    float* agg    = (float*)p;  p += aggB;
    int*   perm   = (int*)p;    p += permB;
    int*   rowptr = (int*)p;    p += rpB;
    int*   cursor = (int*)p;    p += curB;
    int*   bsum   = (int*)p;    p += bsB;
    const size_t needBase = (size_t)(p - (char*)d_ws);
    int2*  pair   = (int2*)p;   // optional
    const size_t needPair = needBase + pairB;

    const int denseBlocks   = (N_NODES + 63) / 64;          // 1563
    const int gatherBlocks  = (N_NODES * 64) / 256;         // 25000
    const int edgeBlocks    = (E + 255) / 256;

    if (ws_size >= needBase) {
        const bool packed = (ws_size >= needPair);
        // ---- CSR build (once, reused by both layers) ----
        hipMemsetAsync(cursor, 0, (size_t)N_NODES * 4, stream);
        hist_kernel<<<edgeBlocks, 256, 0, stream>>>(dst, cursor, E);
        scan1_kernel<<<nScanBlocks, SCAN_TPB, 0, stream>>>(cursor, rowptr, bsum, N_NODES);
        scan2_kernel<<<1, SCAN_TPB, 0, stream>>>(bsum, nScanBlocks);
        scan3_kernel<<<(N_NODES + 255) / 256, 256, 0, stream>>>(rowptr, bsum, cursor, N_NODES, E);
        if (packed)
            pack_kernel<<<edgeBlocks, 256, 0, stream>>>(src, ew, pair, E);
        reorder_perm<<<edgeBlocks, 256, 0, stream>>>(dst, cursor, perm, E);

        if (packed) {
            gather_kernel<true><<<gatherBlocks, 256, 0, stream>>>(x, rowptr, perm, pair, src, ew, agg);
            dense_tiled<true><<<denseBlocks, 256, 0, stream>>>(agg, x, W1r, W1o, b1, out);
            gather_kernel<true><<<gatherBlocks, 256, 0, stream>>>(out, rowptr, perm, pair, src, ew, agg);
            dense_tiled<false><<<denseBlocks, 256, 0, stream>>>(agg, out, W2r, W2o, b2, out);
        } else {
            gather_kernel<false><<<gatherBlocks, 256, 0, stream>>>(x, rowptr, perm, nullptr, src, ew, agg);
            dense_tiled<true><<<denseBlocks, 256, 0, stream>>>(agg, x, W1r, W1o, b1, out);
            gather_kernel<false><<<gatherBlocks, 256, 0, stream>>>(out, rowptr, perm, nullptr, src, ew, agg);
            dense_tiled<false><<<denseBlocks, 256, 0, stream>>>(agg, out, W2r, W2o, b2, out);
        }
    } else {
        // ---- legacy atomic path (needs only agg) ----
        const int scatterBlocks = (int)(((long long)E * 64 + 255) / 256);
        hipMemsetAsync(agg, 0, aggB, stream);
        scatter_kernel<<<scatterBlocks, 256, 0, stream>>>(x, src, dst, ew, agg, E);
        dense_tiled<true><<<denseBlocks, 256, 0, stream>>>(agg, x, W1r, W1o, b1, out);
        hipMemsetAsync(agg, 0, aggB, stream);
        scatter_kernel<<<scatterBlocks, 256, 0, stream>>>(out, src, dst, ew, agg, E);
        dense_tiled<false><<<denseBlocks, 256, 0, stream>>>(agg, out, W2r, W2o, b2, out);
    }
}